// Round 2
// baseline (185.379 us; speedup 1.0000x reference)
//
#include <hip/hip_runtime.h>

// GARCH(1,1) path generation, 3 independent series, N = 24*131072 steps each.
//   v_t = omega + alpha*p_{t-1}^2 + beta*v_{t-1};  p_t = mu + z_t*sqrt(v_t); p_0 = 0.
// out[s*N + t] = p_t of series s.
//
// Contraction/burn-in parallelization: each thread owns K_OUT consecutive
// outputs, started WARM steps early from the steady-state guess
// v = omega/(1-alpha-beta). Log-decay ~ -0.047/step, sigma 0.12*sqrt(W):
// at W=512 a +5-sigma tail still leaves ~5e-5 relative v error (threshold 3e-2).
// Chunks whose window crosses t=0 replay exactly from (p,v)=(0,0).
//
// R1: K_OUT 256->64, WARM 768->512 (4x waves), depth-3 float4 prefetch
// (loads independent of the serial chain -> latency hidden), raw v_sqrt_f32.

#define K_OUT 64
#define WARM  512

__global__ __launch_bounds__(256) void garch_scan_kernel(
    const float* __restrict__ params,   // (3,4): [mu, omega, alpha, beta]
    const float* __restrict__ noise,    // (3,N)
    float* __restrict__ out,            // (3,N)
    int N)
{
    const int cps = N / K_OUT;
    const int gid = blockIdx.x * 256 + threadIdx.x;
    if (gid >= 3 * cps) return;
    const int s = gid / cps;
    const int c = gid - s * cps;

    const float mu    = params[s * 4 + 0];
    const float omega = params[s * 4 + 1];
    const float alpha = params[s * 4 + 2];
    const float beta  = params[s * 4 + 3];

    const float*  z  = noise + (size_t)s * N;
    const float4* z4 = (const float4*)z;
    float*        o  = out + (size_t)s * N;
    float4*       o4 = (float4*)o;

    const int ostart = c * K_OUT;

    if (ostart <= WARM) {
        // window crosses t=0: replay exactly from the true init (27 threads)
        float p = 0.0f, v = 0.0f;
        if (c == 0) o[0] = 0.0f;
        const int tend = ostart + K_OUT;
        for (int t = 1; t < tend; ++t) {
            v = fmaf(alpha, p * p, fmaf(beta, v, omega));
            p = fmaf(z[t], __builtin_amdgcn_sqrtf(v), mu);
            if (t >= ostart) o[t] = p;
        }
        return;
    }

    // steady-state guess; contraction over WARM steps washes out the error
    float p = 0.0f;
    float v = omega / fmaxf(1.0f - alpha - beta, 0.02f);

    const int q0   = (ostart - WARM) >> 2;       // first float4 index (aligned)
    const int WI   = WARM / 4;                   // warm iterations (128)
    const int TOT  = (WARM + K_OUT) / 4;         // total iterations (144)
    const int qmax = (N >> 2) - 1;

    // depth-3 rotating prefetch: loads are independent of the recurrence
    float4 za = z4[q0];
    float4 zb = z4[min(q0 + 1, qmax)];
    float4 zc = z4[min(q0 + 2, qmax)];

    for (int it = 0; it < TOT; ++it) {
        float4 zn = z4[min(q0 + it + 3, qmax)];
        float4 pq;
        v = fmaf(alpha, p*p, fmaf(beta, v, omega)); p = fmaf(za.x, __builtin_amdgcn_sqrtf(v), mu); pq.x = p;
        v = fmaf(alpha, p*p, fmaf(beta, v, omega)); p = fmaf(za.y, __builtin_amdgcn_sqrtf(v), mu); pq.y = p;
        v = fmaf(alpha, p*p, fmaf(beta, v, omega)); p = fmaf(za.z, __builtin_amdgcn_sqrtf(v), mu); pq.z = p;
        v = fmaf(alpha, p*p, fmaf(beta, v, omega)); p = fmaf(za.w, __builtin_amdgcn_sqrtf(v), mu); pq.w = p;
        if (it >= WI) o4[q0 + it] = pq;
        za = zb; zb = zc; zc = zn;
    }
}

extern "C" void kernel_launch(void* const* d_in, const int* in_sizes, int n_in,
                              void* d_out, int out_size, void* d_ws, size_t ws_size,
                              hipStream_t stream) {
    const float* params = (const float*)d_in[0];
    const float* noise  = (const float*)d_in[1];
    float* out = (float*)d_out;

    const int N = in_sizes[1] / 3;          // 3,145,728
    const int cps = N / K_OUT;              // 49,152
    const int total = 3 * cps;              // 147,456 threads
    const int block = 256;
    const int grid = (total + block - 1) / block;

    garch_scan_kernel<<<grid, block, 0, stream>>>(params, noise, out, N);
}

// Round 3
// 43.358 us; speedup vs baseline: 4.2755x; 4.2755x over previous
//
#include <hip/hip_runtime.h>

// GARCH(1,1) paths, 3 series, N = 24*131072.
//   v_t = omega + alpha*p_{t-1}^2 + beta*v_{t-1};  p_t = mu + z_t*sqrt(v_t); p_0=0.
// out[s*N + t] = p_t.
//
// R2: whole-window LDS staging. Within a block, thread c owns outputs
// [B0+64c, B0+64c+64) and warms up 512 steps earlier; the union of all 128
// threads' read-windows is ONE contiguous region of 128*64+512 = 8704 floats
// (34.8 KB) -> stage it coalesced into LDS once, sync once, then each thread
// scans 576 steps from LDS (ds_read_b128 every 4 steps, depth-2 prefetch).
// XOR swizzle a ^= ((a>>6)&7)<<2 on the dword index keeps 16B alignment and
// makes both the staging writes and the strided reads bank-conflict-free.
// Threads whose window crosses t=0 (block 0, tid<=8) replay exactly from
// (p,v)=(0,0) through the same loop (shorter trip count, no extra barriers).

#define NSER     3
#define KOUT     64
#define BTHREADS 128
#define TILE     (BTHREADS * KOUT)     // 8192 outputs per block
#define WARM     512
#define WIN      (TILE + WARM)         // 8704 floats in LDS (34.8 KB)
#define NQ       ((WARM + KOUT) / 4)   // 144 quads per full scan

__device__ __forceinline__ int swz(int a) {        // dword-index swizzle
    return a ^ (((a >> 6) & 7) << 2);              // keeps a%4 (16B alignment)
}

__global__ __launch_bounds__(BTHREADS) void garch_kernel(
    const float* __restrict__ params,   // (3,4): [mu, omega, alpha, beta]
    const float* __restrict__ noise,    // (3,N)
    float* __restrict__ out,            // (3,N)
    int N)
{
    __shared__ __align__(16) float W[WIN];

    const int nblk = N / TILE;                 // 384 blocks per series
    const int bid  = blockIdx.x;
    const int s    = bid / nblk;
    const int b    = bid - s * nblk;
    const int tid  = threadIdx.x;
    const int B0   = b * TILE;

    const float mu    = params[s * 4 + 0];
    const float omega = params[s * 4 + 1];
    const float alpha = params[s * 4 + 2];
    const float beta  = params[s * 4 + 3];

    const float4* z4 = (const float4*)(noise + (size_t)s * N);

    // ---- stage window z[B0-WARM .. B0+TILE) into LDS, coalesced ----
    {
        const int g4base = (B0 >> 2) - (WARM >> 2);   // negative only for b==0
        const int q4max  = (N >> 2) - 1;
        #pragma unroll
        for (int i = 0; i < WIN / 4 / BTHREADS; ++i) {   // 17 float4s/thread
            int gq = g4base + i * BTHREADS + tid;
            gq = max(gq, 0); gq = min(gq, q4max);
            float4 val = z4[gq];
            int pa = swz(4 * (i * BTHREADS + tid));
            __builtin_assume((pa & 3) == 0);
            *(float4*)&W[pa] = val;
        }
    }
    __syncthreads();

    // ---- per-thread scan ----
    const int ostart = B0 + tid * KOUT;
    int   i0, nq, out_from;
    float p, v;
    if (ostart <= WARM) {                  // exact replay (block 0, tid<=8)
        i0 = WARM;                         // W[WARM + t] == z[t]
        nq = 16 * tid + 16;
        out_from = 16 * tid;
        p = 0.0f; v = 0.0f;
    } else {                               // warm-up from steady-state guess
        i0 = tid * KOUT;                   // W[i0 + dt] == z[t0 + dt]
        nq = NQ;
        out_from = NQ - KOUT / 4;          // 128
        p = 0.0f;
        v = omega / fmaxf(1.0f - alpha - beta, 0.02f);
    }
    float4* o4 = (float4*)(out + (size_t)s * N) + (B0 >> 2) + 16 * tid;

    #define LDQ(M) ({ int _a = i0 + 4 * (M); _a = min(_a, WIN - 4);          \
                      int _p = swz(_a); __builtin_assume((_p & 3) == 0);     \
                      *(const float4*)&W[_p]; })

    float4 qa = LDQ(0);
    float4 qb = LDQ(1);

    for (int m = 0; m < nq; ++m) {
        float4 qn = LDQ(m + 2);            // depth-2 rotating prefetch
        float4 pq;
        if (m == 0) {
            pq.x = p;                      // t==t0 slot: initial p (o[0]=0)
        } else {
            v = fmaf(alpha, p * p, fmaf(beta, v, omega));
            p = fmaf(qa.x, __builtin_amdgcn_sqrtf(v), mu); pq.x = p;
        }
        v = fmaf(alpha, p * p, fmaf(beta, v, omega));
        p = fmaf(qa.y, __builtin_amdgcn_sqrtf(v), mu); pq.y = p;
        v = fmaf(alpha, p * p, fmaf(beta, v, omega));
        p = fmaf(qa.z, __builtin_amdgcn_sqrtf(v), mu); pq.z = p;
        v = fmaf(alpha, p * p, fmaf(beta, v, omega));
        p = fmaf(qa.w, __builtin_amdgcn_sqrtf(v), mu); pq.w = p;

        if (m >= out_from) o4[m - out_from] = pq;
        qa = qb; qb = qn;
    }
    #undef LDQ
}

extern "C" void kernel_launch(void* const* d_in, const int* in_sizes, int n_in,
                              void* d_out, int out_size, void* d_ws, size_t ws_size,
                              hipStream_t stream) {
    const float* params = (const float*)d_in[0];
    const float* noise  = (const float*)d_in[1];
    float* out = (float*)d_out;

    const int N = in_sizes[1] / NSER;       // 3,145,728
    const int grid = NSER * (N / TILE);     // 1152 blocks

    garch_kernel<<<grid, BTHREADS, 0, stream>>>(params, noise, out, N);
}